// Round 4
// baseline (416.965 us; speedup 1.0000x reference)
//
#include <hip/hip_runtime.h>

// dijetReinforceLayer via MFMA, register-direct B fragments (R4).
// out[n,o,s] = b[o] + sum_{c,j} W[o,c,j] * din[n,c,s,j]
// GEMM: out[o, col] = sum_k A[o,k] B[k,col], col=(n,s), K=96.
// k-order: k=2c+j (j=0,1, x pairs), k=64+c (j=2, d part).
//
// R3 post-mortem: latency-bound (occupancy 23%, VALU 16%, HBM 22%, MFMA 1.3%):
// 46KB LDS -> 9 waves/CU, and global->LDS->frag round trip with 3 barriers per
// tiny work unit. R4: B fragments loaded straight to registers (per-lane float2/
// float strided loads; each byte fetched once, wave-local L1 coalescing), A (W)
// loaded once per wave from L1-hot global, LDS reduced to per-wave 6.4 KB output
// transpose buffer. 20 waves/CU, 48 outstanding loads/group, 2 barriers/group.
//
// Verified mappings (m89/m91, R3 passed): A[m=lane&15][k=quad*8+j],
// B[k=quad*8+j][col=lane&15], D: col=lane&15, row=quad*4+reg.

#define ND 32
#define NPAIR 6
#define GSAMP 8                 // samples per wave-iteration (48 cols = 3 tiles)
#define OSTR 200                // obuf dword stride per sample (192 + 8 pad)
#define BT 256
#define WPB 4                   // waves per block

typedef __attribute__((ext_vector_type(8))) short bf16x8;
typedef __attribute__((ext_vector_type(4))) float f32x4;

union frag_u { bf16x8 v; unsigned u[4]; };

// pack two fp32 -> two bf16 (truncate; same numerics as R3's passing run)
__device__ __forceinline__ unsigned pack2(float lo, float hi) {
    return __builtin_amdgcn_perm(__float_as_uint(hi), __float_as_uint(lo), 0x07060302u);
}

__global__ __launch_bounds__(BT, 5) void dijet_mfma2(
    const float* __restrict__ x,    // [N, 32, 12]
    const float* __restrict__ d,    // [N, 32, 6]
    const float* __restrict__ W,    // [32, 32, 3]
    const float* __restrict__ bias, // [32]
    float* __restrict__ out,        // [N, 32, 6]
    int N, int iters, int totgroups)
{
    __shared__ __align__(16) float obuf[WPB][GSAMP * OSTR];  // 25.6 KB

    const int wave  = threadIdx.x >> 6;
    const int lane  = threadIdx.x & 63;
    const int row16 = lane & 15;
    const int quad  = lane >> 4;

    // ---- A fragments straight from global W (12 KB, L1-hot), reordered k ----
    frag_u Af[2][3];
#pragma unroll
    for (int ot = 0; ot < 2; ++ot) {
        const float* wbase = W + (ot * 16 + row16) * 96;   // W[o, 0, 0]
#pragma unroll
        for (int ks = 0; ks < 2; ++ks) {
#pragma unroll
            for (int cc = 0; cc < 4; ++cc) {
                int c = ks * 16 + quad * 4 + cc;
                Af[ot][ks].u[cc] = pack2(wbase[c * 3 + 0], wbase[c * 3 + 1]);
            }
        }
#pragma unroll
        for (int cc = 0; cc < 4; ++cc) {
            int c0 = quad * 8 + 2 * cc;
            Af[ot][2].u[cc] = pack2(wbase[c0 * 3 + 2], wbase[(c0 + 1) * 3 + 2]);
        }
    }
    const float4 bv0 = *(const float4*)(bias + quad * 4);
    const float4 bv1 = *(const float4*)(bias + 16 + quad * 4);

    const int gw0    = blockIdx.x * WPB + wave;
    const int stride = gridDim.x * WPB;

    for (int it = 0; it < iters; ++it) {          // uniform count -> barriers safe
        const int g      = gw0 + it * stride;
        const bool active = g < totgroups;
        const int n0     = active ? g * GSAMP : 0;

#pragma unroll
        for (int ct = 0; ct < 3; ++ct) {
            const int col = ct * 16 + row16;       // 0..47
            const int nl  = col / 6;
            const int s   = col - nl * 6;
            const int n   = n0 + nl;
            const bool ld = active && (n < N);

            const float* xp = x + (size_t)n * 384 + 2 * s;  // x[n,0,2s] (8B aligned)
            const float* dp = d + (size_t)n * 192 + s;      // d[n,0,s]

            float2 xv[8];
            float  dv[8];
#pragma unroll
            for (int cc = 0; cc < 4; ++cc) {
                xv[cc]     = ld ? *(const float2*)(xp + (quad * 4 + cc) * 12)
                                : make_float2(0.f, 0.f);
                xv[4 + cc] = ld ? *(const float2*)(xp + (16 + quad * 4 + cc) * 12)
                                : make_float2(0.f, 0.f);
            }
#pragma unroll
            for (int j = 0; j < 8; ++j)
                dv[j] = ld ? dp[(quad * 8 + j) * 6] : 0.f;

            frag_u B0, B1, B2;
#pragma unroll
            for (int cc = 0; cc < 4; ++cc) {
                B0.u[cc] = pack2(xv[cc].x,     xv[cc].y);
                B1.u[cc] = pack2(xv[4 + cc].x, xv[4 + cc].y);
                B2.u[cc] = pack2(dv[2 * cc],   dv[2 * cc + 1]);
            }

            f32x4 a0 = (f32x4){bv0.x, bv0.y, bv0.z, bv0.w};
            f32x4 a1 = (f32x4){bv1.x, bv1.y, bv1.z, bv1.w};
            a0 = __builtin_amdgcn_mfma_f32_16x16x32_bf16(Af[0][0].v, B0.v, a0, 0, 0, 0);
            a0 = __builtin_amdgcn_mfma_f32_16x16x32_bf16(Af[0][1].v, B1.v, a0, 0, 0, 0);
            a0 = __builtin_amdgcn_mfma_f32_16x16x32_bf16(Af[0][2].v, B2.v, a0, 0, 0, 0);
            a1 = __builtin_amdgcn_mfma_f32_16x16x32_bf16(Af[1][0].v, B0.v, a1, 0, 0, 0);
            a1 = __builtin_amdgcn_mfma_f32_16x16x32_bf16(Af[1][1].v, B1.v, a1, 0, 0, 0);
            a1 = __builtin_amdgcn_mfma_f32_16x16x32_bf16(Af[1][2].v, B2.v, a1, 0, 0, 0);

            // scatter D -> per-wave padded obuf: [nl][o*6 + s]
            float* ob = &obuf[wave][nl * OSTR + s];
#pragma unroll
            for (int r = 0; r < 4; ++r) {
                ob[(quad * 4 + r) * 6]        = a0[r];
                ob[(16 + quad * 4 + r) * 6]   = a1[r];
            }
        }

        __syncthreads();   // obuf writes visible (block-wide: simple & safe)

        // coalesced writeback: 8 samples * 192 floats = 1536, 6 float4/lane
        float* og = out + (size_t)n0 * 192;
#pragma unroll
        for (int k = 0; k < 6; ++k) {
            int F  = 4 * (lane + k * 64);      // 0..1532
            int ns = F / 192;
            int wi = F - ns * 192;
            if (active && (n0 + ns) < N)
                *(float4*)(og + ns * 192 + wi) =
                    *(const float4*)(&obuf[wave][ns * OSTR + wi]);
        }

        __syncthreads();   // protect next iteration's obuf writes
    }
}

extern "C" void kernel_launch(void* const* d_in, const int* in_sizes, int n_in,
                              void* d_out, int out_size, void* d_ws, size_t ws_size,
                              hipStream_t stream) {
    const float* x = (const float*)d_in[0];
    const float* d = (const float*)d_in[1];
    const float* W = (const float*)d_in[2];
    const float* b = (const float*)d_in[3];
    float* out = (float*)d_out;

    int N = in_sizes[0] / (ND * 2 * NPAIR);
    int totgroups = (N + GSAMP - 1) / GSAMP;

    int blocks = 1280;                       // 5 blocks/CU fill, W-load amortized 4x
    int totwaves = blocks * WPB;
    int iters = (totgroups + totwaves - 1) / totwaves;

    dijet_mfma2<<<blocks, BT, 0, stream>>>(x, d, W, b, out, N, iters, totgroups);
}